// Round 7
// baseline (244.951 us; speedup 1.0000x reference)
//
#include <hip/hip_runtime.h>
#include <hip/hip_bf16.h>
#include <stdint.h>

#define NNODE 65536
#define NEDGE 65536
#define ETOT  (NNODE + NEDGE)
#define INC   512
#define OUTC  256
#define NEG_SLOPE 0.2f
#define SLOTCAP 32

typedef __attribute__((ext_vector_type(8))) __bf16 bf16x8;
typedef __attribute__((ext_vector_type(4))) float f32x4;

__device__ __forceinline__ float b2f(unsigned short u) {
  return __uint_as_float(((unsigned int)u) << 16);
}
__device__ __forceinline__ unsigned short f2b(float f) {
  unsigned int u = __float_as_uint(f);
  u += 0x7fffu + ((u >> 16) & 1u);
  return (unsigned short)(u >> 16);
}
__device__ __forceinline__ unsigned int pk2(float lo, float hi) {
  return (unsigned int)f2b(lo) | ((unsigned int)f2b(hi) << 16);
}
__device__ __forceinline__ float lrelu(float v) {
  return v > 0.f ? v : NEG_SLOPE * v;
}

// ---------------- prep: f32 -> bf16 of x (8 elems/lane) + cnt zeroing (replaces memset) ----------
__global__ __launch_bounds__(256) void cvt_x_kernel(const float* __restrict__ x,
                                                    unsigned short* __restrict__ xb,
                                                    int* __restrict__ cnt) {
  if (blockIdx.x < 256) cnt[blockIdx.x * 256 + threadIdx.x] = 0;
  size_t i = ((size_t)blockIdx.x * 256 + threadIdx.x) * 8;
  float4 v0 = *(const float4*)(x + i);
  float4 v1 = *(const float4*)(x + i + 4);
  uint4 o;
  o.x = pk2(v0.x, v0.y);
  o.y = pk2(v0.z, v0.w);
  o.z = pk2(v1.x, v1.y);
  o.w = pk2(v1.z, v1.w);
  *(uint4*)(xb + i) = o;
}

// ---------------- prep: W concat transposed (768x512 bf16) + bias concat ----------------
__global__ __launch_bounds__(256) void prep_w_kernel(
    const float* __restrict__ Wl, const float* __restrict__ Wr, const float* __restrict__ Ws,
    const float* __restrict__ bl, const float* __restrict__ br, const float* __restrict__ bs,
    unsigned short* __restrict__ WT, float* __restrict__ bcat) {
  int i = blockIdx.x * 256 + threadIdx.x;
  if (i < 768 * 512) {
    int o = i >> 9, k = i & 511;
    float v;
    if (o < 256)      v = Wl[k * 256 + o];
    else if (o < 512) v = Wr[k * 256 + (o - 256)];
    else              v = Ws[k * 256 + (o - 512)];
    WT[i] = f2b(v);
  }
  if (i < 768) {
    bcat[i] = (i < 256) ? bl[i] : (i < 512 ? br[i - 256] : bs[i - 512]);
  }
}

// ---------------- persistent fused GEMM: [N,512]bf16 @ [512,768]bf16 -> xl, xr, xs (bf16) --------
// 256 blocks (1/CU), each owns one 256-row panel and walks 3 col-tiles (by=0,1,2 -> xl,xr,xs).
// BK=32, 48 global K-steps, 3-buffer LDS ring (32KB each) staged CONTINUOUSLY across tile
// boundaries (one prologue per CU; epilogue overlaps next tile's staging). Counted vmcnt(4)
// (T4), raw s_barrier + sched_barrier (rule 18), setprio (T5), XCD-bijective placement (T1),
// XOR slot swizzle via pre-swizzled global source (T2, rule 21). Epilogue restage in
// dedicated LDS (ring unharmed).
__global__ __launch_bounds__(512) void gemm_kernel(
    const unsigned short* __restrict__ Xb,   // [65536][512]
    const unsigned short* __restrict__ WT,   // [768][512]
    const float* __restrict__ bcat,          // [768]
    unsigned short* __restrict__ xl,
    unsigned short* __restrict__ xr,
    unsigned short* __restrict__ xs) {
  __shared__ __align__(16) char smem[133120];       // ring 3x32KB = 98304 + eps 34816
  unsigned short* ring = (unsigned short*)smem;     // buf b at b*16384 shorts (A 8192 + B 8192)
  float* epsall = (float*)(smem + 98304);

  const int p = blockIdx.x;                 // 0..255, 1 block per CU
  const int xcd = p & 7;
  const int rowt = xcd * 32 + (p >> 3);     // bijective XCD placement (256 % 8 == 0)
  const int rowBase = rowt * 256;

  const int tid = threadIdx.x;
  const int lane = tid & 63;
  const int w = tid >> 6;
  const int wm = (w >> 2) * 128;
  const int wn = (w & 3) * 64;

  // stage K-step (by2, t2) into ring[buf]: 4 x global_load_lds 16B per thread.
  // LDS dest linear in lane order (m104); global source slot XOR-pre-swizzled (rule 21).
  auto do_stage = [&](int by2, int t2, int buf) {
    const int kk = t2 * 32;
    const int cb2 = by2 * 256;
    const int q = tid;
    const int sl = q & 3;
#pragma unroll
    for (int l = 0; l < 2; ++l) {
      const int r = l * 128 + (q >> 2);            // tile row 0..255
      const int slot = sl ^ ((r >> 1) & 3);        // involution
      const unsigned short* gA = Xb + (size_t)(rowBase + r) * 512 + kk + slot * 8;
      __builtin_amdgcn_global_load_lds(
          (const __attribute__((address_space(1))) void*)gA,
          (__attribute__((address_space(3))) void*)(ring + buf * 16384 + l * 4096 + q * 8), 16, 0, 0);
      const unsigned short* gB = WT + (size_t)(cb2 + r) * 512 + kk + slot * 8;
      __builtin_amdgcn_global_load_lds(
          (const __attribute__((address_space(1))) void*)gB,
          (__attribute__((address_space(3))) void*)(ring + buf * 16384 + 8192 + l * 4096 + q * 8), 16, 0, 0);
    }
  };

  // prologue: 2 K-steps in flight
  do_stage(0, 0, 0);
  do_stage(0, 1, 1);

  for (int by = 0; by < 3; ++by) {
    f32x4 acc[8][4] = {};
#pragma unroll
    for (int t = 0; t < 16; ++t) {
      // wait: step g = by*16+t landed (leave next step flying); drain only at the very end
      if (t < 15) {
        asm volatile("s_waitcnt vmcnt(4)" ::: "memory");
      } else if (by < 2) {
        asm volatile("s_waitcnt vmcnt(4)" ::: "memory");
      } else {
        asm volatile("s_waitcnt vmcnt(0)" ::: "memory");
      }
      __builtin_amdgcn_s_barrier();           // all waves' step-g data landed; buf(g-1) readers done
      __builtin_amdgcn_sched_barrier(0);      // close hoist window (rule 18)

      // issue stage for step g+2 (may belong to next col-tile -> ring never stalls)
      if (t <= 13)      do_stage(by, t + 2, (by + t + 2) % 3);
      else if (by < 2)  do_stage(by + 1, t - 14, (by + t + 2) % 3);

      // fragments for step g from ring[(by+t)%3]
      {
        const unsigned short* As = ring + ((by + t) % 3) * 16384;
        const unsigned short* Bs = As + 8192;
        const int kq = lane >> 4;
        bf16x8 fa[8], fb[4];
#pragma unroll
        for (int m = 0; m < 8; ++m) {
          const int rA = wm + m * 16 + (lane & 15);
          fa[m] = *(const bf16x8*)&As[rA * 32 + ((kq ^ ((rA >> 1) & 3)) << 3)];
        }
#pragma unroll
        for (int n = 0; n < 4; ++n) {
          const int rB = wn + n * 16 + (lane & 15);
          fb[n] = *(const bf16x8*)&Bs[rB * 32 + ((kq ^ ((rB >> 1) & 3)) << 3)];
        }
        __builtin_amdgcn_s_setprio(1);
#pragma unroll
        for (int m = 0; m < 8; ++m)
#pragma unroll
          for (int n = 0; n < 4; ++n)
            acc[m][n] = __builtin_amdgcn_mfma_f32_16x16x32_bf16(fa[m], fb[n], acc[m][n], 0, 0, 0);
        __builtin_amdgcn_s_setprio(0);
      }
    }

    // epilogue for col-tile `by` (per-wave-private LDS slice; ring staging continues untouched).
    // D frag layout: col = lane&15, row = (lane>>4)*4 + j   [m89-verified]
    {
      unsigned short* dst = (by == 0) ? xl : (by == 1) ? xr : xs;
      float* eps = epsall + w * 1088;   // 16x68 f32 private
      const int cb = by * 256;
      float biasn[4];
#pragma unroll
      for (int n = 0; n < 4; ++n) biasn[n] = bcat[cb + wn + n * 16 + (lane & 15)];
#pragma unroll
      for (int m = 0; m < 8; ++m) {
#pragma unroll
        for (int n = 0; n < 4; ++n)
#pragma unroll
          for (int j = 0; j < 4; ++j)
            eps[((lane >> 4) * 4 + j) * 68 + n * 16 + (lane & 15)] = acc[m][n][j] + biasn[n];
#pragma unroll
        for (int it = 0; it < 2; ++it) {
          const int r16 = it * 8 + (lane >> 3);
          const int c8 = (lane & 7) * 8;
          const float* srcp = eps + r16 * 68 + c8;
          float4 v0 = *(const float4*)srcp;
          float4 v1 = *(const float4*)(srcp + 4);
          uint4 o;
          o.x = pk2(v0.x, v0.y);
          o.y = pk2(v0.z, v0.w);
          o.z = pk2(v1.x, v1.y);
          o.w = pk2(v1.z, v1.w);
          *(uint4*)(dst + (size_t)(rowBase + wm + m * 16 + r16) * 256 + wn + c8) = o;
        }
      }
    }
  }
}

// ---------------- per-edge attention logits (half-wave per edge) + direct slot scatter ----------------
__global__ __launch_bounds__(256) void edge_logit_kernel(
    const int* __restrict__ ei,          // [2][NEDGE]
    const unsigned short* __restrict__ xl,
    const unsigned short* __restrict__ xr,
    const float* __restrict__ att,
    int* __restrict__ cnt,
    int* __restrict__ slot_src,          // [NNODE][SLOTCAP]
    float* __restrict__ slot_e) {        // [NNODE][SLOTCAP]
  const int j = blockIdx.x * 8 + (threadIdx.x >> 5);
  const int lane = threadIdx.x & 31;
  int src, dst;
  if (j < NEDGE) { src = ei[j]; dst = ei[NEDGE + j]; }
  else           { src = j - NEDGE; dst = src; }
  const int c = lane * 8;
  uint4 ul = *(const uint4*)(xl + (size_t)src * 256 + c);
  uint4 ur = *(const uint4*)(xr + (size_t)dst * 256 + c);
  float4 a0 = *(const float4*)(att + c);
  float4 a1 = *(const float4*)(att + c + 4);
  float s = lrelu(b2f((unsigned short)ul.x) + b2f((unsigned short)ur.x)) * a0.x
          + lrelu(b2f((unsigned short)(ul.x >> 16)) + b2f((unsigned short)(ur.x >> 16))) * a0.y
          + lrelu(b2f((unsigned short)ul.y) + b2f((unsigned short)ur.y)) * a0.z
          + lrelu(b2f((unsigned short)(ul.y >> 16)) + b2f((unsigned short)(ur.y >> 16))) * a0.w
          + lrelu(b2f((unsigned short)ul.z) + b2f((unsigned short)ur.z)) * a1.x
          + lrelu(b2f((unsigned short)(ul.z >> 16)) + b2f((unsigned short)(ur.z >> 16))) * a1.y
          + lrelu(b2f((unsigned short)ul.w) + b2f((unsigned short)ur.w)) * a1.z
          + lrelu(b2f((unsigned short)(ul.w >> 16)) + b2f((unsigned short)(ur.w >> 16))) * a1.w;
#pragma unroll
  for (int off = 16; off; off >>= 1) s += __shfl_xor(s, off);
  if (lane == 0) {
    const int pos = atomicAdd(&cnt[dst], 1);
    if (pos < SLOTCAP) {
      slot_src[dst * SLOTCAP + pos] = src;
      slot_e[dst * SLOTCAP + pos] = s;
    }
  }
}

// ---------------- per-node softmax + aggregate + cls logit (wave per node) ----------------
__global__ __launch_bounds__(256) void node_kernel(
    const int* __restrict__ cnt,
    const int* __restrict__ slot_src, const float* __restrict__ slot_e,
    const unsigned short* __restrict__ xl,
    const unsigned short* __restrict__ xs,
    const float* __restrict__ conv_bias,
    float* __restrict__ out,
    const float* __restrict__ Wcls, const float* __restrict__ bcls,
    float* __restrict__ logits) {
  const int n = blockIdx.x * 4 + (threadIdx.x >> 6);
  const int lane = threadIdx.x & 63;
  const int base = n * SLOTCAP;
  const int deg = cnt[n];

  float m = -1e30f;
  for (int k = 0; k < deg; ++k) m = fmaxf(m, slot_e[base + k]);
  float denom = 0.f;
  for (int k = 0; k < deg; ++k) denom += __expf(slot_e[base + k] - m);
  const float inv = 1.f / denom;

  const int c = lane * 4;
  float4 accv = {0.f, 0.f, 0.f, 0.f};
  for (int k = 0; k < deg; ++k) {
    const float alpha = __expf(slot_e[base + k] - m) * inv;
    const int src = slot_src[base + k];
    ushort4 u = *(const ushort4*)(xl + (size_t)src * 256 + c);
    accv.x += alpha * b2f(u.x);
    accv.y += alpha * b2f(u.y);
    accv.z += alpha * b2f(u.z);
    accv.w += alpha * b2f(u.w);
  }
  ushort4 s4 = *(const ushort4*)(xs + (size_t)n * 256 + c);
  float4 cb = *(const float4*)(conv_bias + c);
  float4 cur;
  cur.x = b2f(s4.x) + accv.x + cb.x;
  cur.y = b2f(s4.y) + accv.y + cb.y;
  cur.z = b2f(s4.z) + accv.z + cb.z;
  cur.w = b2f(s4.w) + accv.w + cb.w;
  const size_t o = (size_t)n * 256 + c;
  *(float4*)(out + o) = cur;

  float4 wc = *(const float4*)(Wcls + c);
  float part = cur.x * wc.x + cur.y * wc.y + cur.z * wc.z + cur.w * wc.w;
#pragma unroll
  for (int off = 32; off; off >>= 1) part += __shfl_xor(part, off, 64);
  if (lane == 0) logits[n] = part + bcls[0];
}

// ---------------- sinkhorn row softmax + broadcast add (4 blocks per row) ----------------
__global__ __launch_bounds__(256) void sk_kernel(const float* __restrict__ logits,
                                                 float* __restrict__ out) {
  __shared__ float sv[256];
  __shared__ float red[256];
  const int r = blockIdx.x >> 2;
  const int q = blockIdx.x & 3;
  const int t = threadIdx.x;
  const float v = logits[r * 256 + t];
  red[t] = v;
  __syncthreads();
  for (int d = 128; d; d >>= 1) {
    if (t < d) red[t] = fmaxf(red[t], red[t + d]);
    __syncthreads();
  }
  const float mx = red[0];
  __syncthreads();
  const float p = __expf(v - mx);
  red[t] = p;
  __syncthreads();
  for (int d = 128; d; d >>= 1) {
    if (t < d) red[t] += red[t + d];
    __syncthreads();
  }
  const float sum = red[0];
  sv[t] = p / sum;
  __syncthreads();
  const size_t rowbase = (size_t)r * 256 * 256;
  for (int i = q * 64; i < q * 64 + 64; ++i) {
    out[rowbase + (size_t)i * 256 + t] += sv[i];
  }
}

// ---------------- launch ----------------
extern "C" void kernel_launch(void* const* d_in, const int* in_sizes, int n_in,
                              void* d_out, int out_size, void* d_ws, size_t ws_size,
                              hipStream_t stream) {
  const float* x        = (const float*)d_in[0];
  const int*   ei       = (const int*)d_in[2];
  const float* W_self   = (const float*)d_in[5];
  const float* b_self   = (const float*)d_in[6];
  const float* W_l      = (const float*)d_in[7];
  const float* b_l      = (const float*)d_in[8];
  const float* W_r      = (const float*)d_in[9];
  const float* b_r      = (const float*)d_in[10];
  const float* att      = (const float*)d_in[11];
  const float* conv_bias= (const float*)d_in[12];
  const float* W_cls    = (const float*)d_in[13];
  const float* b_cls    = (const float*)d_in[14];
  float* out = (float*)d_out;

  char* ws = (char*)d_ws;
  size_t off = 0;
  auto alloc = [&](size_t bytes) {
    char* p = ws + off;
    off += (bytes + 255) & ~(size_t)255;
    return p;
  };
  unsigned short* xb   = (unsigned short*)alloc((size_t)NNODE * INC * 2);  // dead after gemm
  unsigned short* WT   = (unsigned short*)alloc((size_t)768 * 512 * 2);
  float*          bcat = (float*)alloc(768 * 4);
  unsigned short* xlb  = (unsigned short*)alloc((size_t)NNODE * OUTC * 2);
  unsigned short* xrb  = (unsigned short*)alloc((size_t)NNODE * OUTC * 2);
  unsigned short* xsb  = (unsigned short*)alloc((size_t)NNODE * OUTC * 2);
  int*            cnt  = (int*)alloc((size_t)NNODE * 4);
  float*          logits  = (float*)alloc((size_t)NNODE * 4);
  // slot arrays overlay xb (dead after gemm): 65536*32*(4+4) = 16.8 MB << 64 MB
  int*   slot_src = (int*)xb;
  float* slot_e   = (float*)(xb + (size_t)NNODE * SLOTCAP * 2);
  (void)ws_size; (void)in_sizes; (void)n_in; (void)out_size;

  cvt_x_kernel<<<(NNODE * INC) / (256 * 8), 256, 0, stream>>>(x, xb, cnt);
  prep_w_kernel<<<(768 * 512 + 255) / 256, 256, 0, stream>>>(W_l, W_r, W_self, b_l, b_r, b_self, WT, bcat);
  gemm_kernel<<<256, 512, 0, stream>>>(xb, WT, bcat, xlb, xrb, xsb);
  edge_logit_kernel<<<ETOT / 8, 256, 0, stream>>>(ei, xlb, xrb, att, cnt, slot_src, slot_e);
  node_kernel<<<NNODE / 4, 256, 0, stream>>>(cnt, slot_src, slot_e, xlb, xsb, conv_bias,
                                             out, W_cls, b_cls, logits);
  sk_kernel<<<1024, 256, 0, stream>>>(logits, out);
}

// Round 8
// 199.823 us; speedup vs baseline: 1.2258x; 1.2258x over previous
//
#include <hip/hip_runtime.h>
#include <hip/hip_bf16.h>
#include <stdint.h>

#define NNODE 65536
#define NEDGE 65536
#define ETOT  (NNODE + NEDGE)
#define INC   512
#define OUTC  256
#define NEG_SLOPE 0.2f
#define SLOTCAP 32

typedef __attribute__((ext_vector_type(8))) __bf16 bf16x8;
typedef __attribute__((ext_vector_type(4))) float f32x4;

__device__ __forceinline__ float b2f(unsigned short u) {
  return __uint_as_float(((unsigned int)u) << 16);
}
__device__ __forceinline__ unsigned short f2b(float f) {
  unsigned int u = __float_as_uint(f);
  u += 0x7fffu + ((u >> 16) & 1u);
  return (unsigned short)(u >> 16);
}
__device__ __forceinline__ unsigned int pk2(float lo, float hi) {
  return (unsigned int)f2b(lo) | ((unsigned int)f2b(hi) << 16);
}
__device__ __forceinline__ float lrelu(float v) {
  return v > 0.f ? v : NEG_SLOPE * v;
}

// ---------------- prep: f32 -> bf16 of x (8 elems/lane) + cnt zeroing ----------
__global__ __launch_bounds__(256) void cvt_x_kernel(const float* __restrict__ x,
                                                    unsigned short* __restrict__ xb,
                                                    int* __restrict__ cnt) {
  if (blockIdx.x < 256) cnt[blockIdx.x * 256 + threadIdx.x] = 0;
  size_t i = ((size_t)blockIdx.x * 256 + threadIdx.x) * 8;
  float4 v0 = *(const float4*)(x + i);
  float4 v1 = *(const float4*)(x + i + 4);
  uint4 o;
  o.x = pk2(v0.x, v0.y);
  o.y = pk2(v0.z, v0.w);
  o.z = pk2(v1.x, v1.y);
  o.w = pk2(v1.z, v1.w);
  *(uint4*)(xb + i) = o;
}

// ---------------- prep: W concat transposed (768x512 bf16) + bias concat ----------------
__global__ __launch_bounds__(256) void prep_w_kernel(
    const float* __restrict__ Wl, const float* __restrict__ Wr, const float* __restrict__ Ws,
    const float* __restrict__ bl, const float* __restrict__ br, const float* __restrict__ bs,
    unsigned short* __restrict__ WT, float* __restrict__ bcat) {
  int i = blockIdx.x * 256 + threadIdx.x;
  if (i < 768 * 512) {
    int o = i >> 9, k = i & 511;
    float v;
    if (o < 256)      v = Wl[k * 256 + o];
    else if (o < 512) v = Wr[k * 256 + (o - 256)];
    else              v = Ws[k * 256 + (o - 512)];
    WT[i] = f2b(v);
  }
  if (i < 768) {
    bcat[i] = (i < 256) ? bl[i] : (i < 512 ? br[i - 256] : bs[i - 512]);
  }
}

// ---------------- fused GEMM: [N,512]bf16 @ [512,768]bf16 -> xl, xr, xs (bf16) ------------------
// 8-PHASE fine interleave (m201 recipe @ BK=32): 256x256 tile, 8 waves (2Mx4N, per-wave 128x64).
// 16 K-tiles; 2 phases per K-tile, each phase = {4-8 ds_read_b128 | stage 1 half-tile (2
// global_load_lds) | s_barrier | lgkmcnt(0)+sched_barrier | 16 MFMA setprio cluster | s_barrier}.
// 3-buffer LDS ring (32KB each, 96KB total; epilogue reuses ring). Stage leads compute by 4
// phases; counted vmcnt(4) ONCE per K-tile (end of odd phase), vmcnt(0) only at tail c=14.
// Ledger: stage@phase p -> buf (c+2)%3, freed at p-1 (reads retired via lgkmcnt before its
// barriers); reads of tile c guarded by odd-phase(c-1) vmcnt(4)+barrier; vmcnt retires in order.
// T1 XCD swizzle (768 = 8 x 96; col-tiles of a row-panel concurrent on one XCD -> A L2-shared).
// T2 XOR slot swizzle via pre-swizzled global source (rule 21). T5 setprio.
__global__ __launch_bounds__(512) void gemm_kernel(
    const unsigned short* __restrict__ Xb,   // [65536][512]
    const unsigned short* __restrict__ WT,   // [768][512]
    const float* __restrict__ bcat,          // [768]
    unsigned short* __restrict__ xl,
    unsigned short* __restrict__ xr,
    unsigned short* __restrict__ xs) {
  __shared__ __align__(16) char smem[98304];      // ring: 3 bufs x (A 16KB + B 16KB)
  unsigned short* ring = (unsigned short*)smem;   // buf b at b*16384 shorts; B at +8192

  const int wid = blockIdx.x;
  const int xcd = wid & 7;
  const int local = wid >> 3;              // 0..95
  const int by = local % 3;                // col tile 0..2  (0->xl, 1->xr, 2->xs)
  const int rowt = xcd * 32 + local / 3;   // row tile 0..255
  const int rowBase = rowt * 256;
  const int colBase = by * 256;

  const int tid = threadIdx.x;
  const int lane = tid & 63;
  const int w = tid >> 6;        // wave 0..7
  const int wm = (w >> 2) * 128; // wave row offset
  const int wn = (w & 3) * 64;   // wave col offset

  f32x4 acc[8][4] = {};

  // stage A-half (hf=0) or B-half (hf=1) of K-tile c into ring[c%3]: 2 x global_load_lds 16B.
  auto stageh = [&](int c, int hf) {
    const int kk = c * 32;
    const int buf = c % 3;
    const int q = tid;
    const int sl = q & 3;
    const unsigned short* basep = hf ? (WT + (size_t)colBase * 512) : (Xb + (size_t)rowBase * 512);
    unsigned short* ldst = ring + buf * 16384 + hf * 8192;
#pragma unroll
    for (int l = 0; l < 2; ++l) {
      const int r = l * 128 + (q >> 2);            // tile row 0..255
      const int slot = sl ^ ((r >> 1) & 3);        // involution (rule 21)
      const unsigned short* g = basep + (size_t)r * 512 + kk + slot * 8;
      __builtin_amdgcn_global_load_lds(
          (const __attribute__((address_space(1))) void*)g,
          (__attribute__((address_space(3))) void*)(ldst + l * 4096 + q * 8), 16, 0, 0);
    }
  };

  // prologue: tiles 0 and 1 fully staged; tile 0 landed (tile 1's 4 loads may fly)
  stageh(0, 0); stageh(0, 1);
  stageh(1, 0); stageh(1, 1);
  asm volatile("s_waitcnt vmcnt(4)" ::: "memory");
  __builtin_amdgcn_s_barrier();

#pragma unroll
  for (int c = 0; c < 16; ++c) {
    const unsigned short* As = ring + (c % 3) * 16384;
    const unsigned short* Bs = As + 8192;
    const int kq = lane >> 4;
    bf16x8 fa[8], fb[4];

    // ---- even phase: read A m0-3 + B n0-3 (8 ds_read_b128); stage A-half of tile c+2 ----
#pragma unroll
    for (int m = 0; m < 4; ++m) {
      const int rA = wm + m * 16 + (lane & 15);
      fa[m] = *(const bf16x8*)&As[rA * 32 + ((kq ^ ((rA >> 1) & 3)) << 3)];
    }
#pragma unroll
    for (int n = 0; n < 4; ++n) {
      const int rB = wn + n * 16 + (lane & 15);
      fb[n] = *(const bf16x8*)&Bs[rB * 32 + ((kq ^ ((rB >> 1) & 3)) << 3)];
    }
    if (c + 2 < 16) stageh(c + 2, 0);
    __builtin_amdgcn_s_barrier();
    asm volatile("s_waitcnt lgkmcnt(0)" ::: "memory");
    __builtin_amdgcn_sched_barrier(0);
    __builtin_amdgcn_s_setprio(1);
#pragma unroll
    for (int m = 0; m < 4; ++m)
#pragma unroll
      for (int n = 0; n < 4; ++n)
        acc[m][n] = __builtin_amdgcn_mfma_f32_16x16x32_bf16(fa[m], fb[n], acc[m][n], 0, 0, 0);
    __builtin_amdgcn_s_setprio(0);
    __builtin_amdgcn_s_barrier();

    // ---- odd phase: read A m4-7 (4 ds_read_b128); stage B-half of tile c+2 ----
#pragma unroll
    for (int m = 4; m < 8; ++m) {
      const int rA = wm + m * 16 + (lane & 15);
      fa[m] = *(const bf16x8*)&As[rA * 32 + ((kq ^ ((rA >> 1) & 3)) << 3)];
    }
    if (c + 2 < 16) stageh(c + 2, 1);
    __builtin_amdgcn_s_barrier();
    asm volatile("s_waitcnt lgkmcnt(0)" ::: "memory");
    __builtin_amdgcn_sched_barrier(0);
    __builtin_amdgcn_s_setprio(1);
#pragma unroll
    for (int m = 4; m < 8; ++m)
#pragma unroll
      for (int n = 0; n < 4; ++n)
        acc[m][n] = __builtin_amdgcn_mfma_f32_16x16x32_bf16(fa[m], fb[n], acc[m][n], 0, 0, 0);
    __builtin_amdgcn_s_setprio(0);
    // counted wait: tile c+1 (staged 2 phases back) landed; tile c+2's 4 loads may fly
    if (c <= 13)      asm volatile("s_waitcnt vmcnt(4)" ::: "memory");
    else if (c == 14) asm volatile("s_waitcnt vmcnt(0)" ::: "memory");
    __builtin_amdgcn_s_barrier();
  }

  // epilogue: bf16 outputs; per-wave-private restage in ring LDS for 128B-contiguous stores.
  // D frag layout: col = lane&15, row = (lane>>4)*4 + j   [m89-verified]
  {
    unsigned short* dst = (by == 0) ? xl : (by == 1) ? xr : xs;
    float* eps = (float*)smem + w * 1088;   // 16x68 f32 private slice (34816B < 96KB)
    float biasn[4];
#pragma unroll
    for (int n = 0; n < 4; ++n) biasn[n] = bcat[colBase + wn + n * 16 + (lane & 15)];
#pragma unroll
    for (int m = 0; m < 8; ++m) {
#pragma unroll
      for (int n = 0; n < 4; ++n)
#pragma unroll
        for (int j = 0; j < 4; ++j)
          eps[((lane >> 4) * 4 + j) * 68 + n * 16 + (lane & 15)] = acc[m][n][j] + biasn[n];
#pragma unroll
      for (int it = 0; it < 2; ++it) {
        const int r16 = it * 8 + (lane >> 3);
        const int c8 = (lane & 7) * 8;
        const float* srcp = eps + r16 * 68 + c8;
        float4 v0 = *(const float4*)srcp;
        float4 v1 = *(const float4*)(srcp + 4);
        uint4 o;
        o.x = pk2(v0.x, v0.y);
        o.y = pk2(v0.z, v0.w);
        o.z = pk2(v1.x, v1.y);
        o.w = pk2(v1.z, v1.w);
        *(uint4*)(dst + (size_t)(rowBase + wm + m * 16 + r16) * 256 + wn + c8) = o;
      }
    }
  }
}

// ---------------- per-edge attention logits (half-wave per edge) + direct slot scatter ----------------
__global__ __launch_bounds__(256) void edge_logit_kernel(
    const int* __restrict__ ei,          // [2][NEDGE]
    const unsigned short* __restrict__ xl,
    const unsigned short* __restrict__ xr,
    const float* __restrict__ att,
    int* __restrict__ cnt,
    int* __restrict__ slot_src,          // [NNODE][SLOTCAP]
    float* __restrict__ slot_e) {        // [NNODE][SLOTCAP]
  const int j = blockIdx.x * 8 + (threadIdx.x >> 5);
  const int lane = threadIdx.x & 31;
  int src, dst;
  if (j < NEDGE) { src = ei[j]; dst = ei[NEDGE + j]; }
  else           { src = j - NEDGE; dst = src; }
  const int c = lane * 8;
  uint4 ul = *(const uint4*)(xl + (size_t)src * 256 + c);
  uint4 ur = *(const uint4*)(xr + (size_t)dst * 256 + c);
  float4 a0 = *(const float4*)(att + c);
  float4 a1 = *(const float4*)(att + c + 4);
  float s = lrelu(b2f((unsigned short)ul.x) + b2f((unsigned short)ur.x)) * a0.x
          + lrelu(b2f((unsigned short)(ul.x >> 16)) + b2f((unsigned short)(ur.x >> 16))) * a0.y
          + lrelu(b2f((unsigned short)ul.y) + b2f((unsigned short)ur.y)) * a0.z
          + lrelu(b2f((unsigned short)(ul.y >> 16)) + b2f((unsigned short)(ur.y >> 16))) * a0.w
          + lrelu(b2f((unsigned short)ul.z) + b2f((unsigned short)ur.z)) * a1.x
          + lrelu(b2f((unsigned short)(ul.z >> 16)) + b2f((unsigned short)(ur.z >> 16))) * a1.y
          + lrelu(b2f((unsigned short)ul.w) + b2f((unsigned short)ur.w)) * a1.z
          + lrelu(b2f((unsigned short)(ul.w >> 16)) + b2f((unsigned short)(ur.w >> 16))) * a1.w;
#pragma unroll
  for (int off = 16; off; off >>= 1) s += __shfl_xor(s, off);
  if (lane == 0) {
    const int pos = atomicAdd(&cnt[dst], 1);
    if (pos < SLOTCAP) {
      slot_src[dst * SLOTCAP + pos] = src;
      slot_e[dst * SLOTCAP + pos] = s;
    }
  }
}

// ---------------- per-node softmax + aggregate + cls logit (wave per node) ----------------
__global__ __launch_bounds__(256) void node_kernel(
    const int* __restrict__ cnt,
    const int* __restrict__ slot_src, const float* __restrict__ slot_e,
    const unsigned short* __restrict__ xl,
    const unsigned short* __restrict__ xs,
    const float* __restrict__ conv_bias,
    float* __restrict__ out,
    const float* __restrict__ Wcls, const float* __restrict__ bcls,
    float* __restrict__ logits) {
  const int n = blockIdx.x * 4 + (threadIdx.x >> 6);
  const int lane = threadIdx.x & 63;
  const int base = n * SLOTCAP;
  const int deg = cnt[n];

  float m = -1e30f;
  for (int k = 0; k < deg; ++k) m = fmaxf(m, slot_e[base + k]);
  float denom = 0.f;
  for (int k = 0; k < deg; ++k) denom += __expf(slot_e[base + k] - m);
  const float inv = 1.f / denom;

  const int c = lane * 4;
  float4 accv = {0.f, 0.f, 0.f, 0.f};
  for (int k = 0; k < deg; ++k) {
    const float alpha = __expf(slot_e[base + k] - m) * inv;
    const int src = slot_src[base + k];
    ushort4 u = *(const ushort4*)(xl + (size_t)src * 256 + c);
    accv.x += alpha * b2f(u.x);
    accv.y += alpha * b2f(u.y);
    accv.z += alpha * b2f(u.z);
    accv.w += alpha * b2f(u.w);
  }
  ushort4 s4 = *(const ushort4*)(xs + (size_t)n * 256 + c);
  float4 cb = *(const float4*)(conv_bias + c);
  float4 cur;
  cur.x = b2f(s4.x) + accv.x + cb.x;
  cur.y = b2f(s4.y) + accv.y + cb.y;
  cur.z = b2f(s4.z) + accv.z + cb.z;
  cur.w = b2f(s4.w) + accv.w + cb.w;
  const size_t o = (size_t)n * 256 + c;
  *(float4*)(out + o) = cur;

  float4 wc = *(const float4*)(Wcls + c);
  float part = cur.x * wc.x + cur.y * wc.y + cur.z * wc.z + cur.w * wc.w;
#pragma unroll
  for (int off = 32; off; off >>= 1) part += __shfl_xor(part, off, 64);
  if (lane == 0) logits[n] = part + bcls[0];
}

// ---------------- sinkhorn row softmax + broadcast add (4 blocks per row) ----------------
__global__ __launch_bounds__(256) void sk_kernel(const float* __restrict__ logits,
                                                 float* __restrict__ out) {
  __shared__ float sv[256];
  __shared__ float red[256];
  const int r = blockIdx.x >> 2;
  const int q = blockIdx.x & 3;
  const int t = threadIdx.x;
  const float v = logits[r * 256 + t];
  red[t] = v;
  __syncthreads();
  for (int d = 128; d; d >>= 1) {
    if (t < d) red[t] = fmaxf(red[t], red[t + d]);
    __syncthreads();
  }
  const float mx = red[0];
  __syncthreads();
  const float p = __expf(v - mx);
  red[t] = p;
  __syncthreads();
  for (int d = 128; d; d >>= 1) {
    if (t < d) red[t] += red[t + d];
    __syncthreads();
  }
  const float sum = red[0];
  sv[t] = p / sum;
  __syncthreads();
  const size_t rowbase = (size_t)r * 256 * 256;
  for (int i = q * 64; i < q * 64 + 64; ++i) {
    out[rowbase + (size_t)i * 256 + t] += sv[i];
  }
}

// ---------------- launch ----------------
extern "C" void kernel_launch(void* const* d_in, const int* in_sizes, int n_in,
                              void* d_out, int out_size, void* d_ws, size_t ws_size,
                              hipStream_t stream) {
  const float* x        = (const float*)d_in[0];
  const int*   ei       = (const int*)d_in[2];
  const float* W_self   = (const float*)d_in[5];
  const float* b_self   = (const float*)d_in[6];
  const float* W_l      = (const float*)d_in[7];
  const float* b_l      = (const float*)d_in[8];
  const float* W_r      = (const float*)d_in[9];
  const float* b_r      = (const float*)d_in[10];
  const float* att      = (const float*)d_in[11];
  const float* conv_bias= (const float*)d_in[12];
  const float* W_cls    = (const float*)d_in[13];
  const float* b_cls    = (const float*)d_in[14];
  float* out = (float*)d_out;

  char* ws = (char*)d_ws;
  size_t off = 0;
  auto alloc = [&](size_t bytes) {
    char* p = ws + off;
    off += (bytes + 255) & ~(size_t)255;
    return p;
  };
  unsigned short* xb   = (unsigned short*)alloc((size_t)NNODE * INC * 2);  // dead after gemm
  unsigned short* WT   = (unsigned short*)alloc((size_t)768 * 512 * 2);
  float*          bcat = (float*)alloc(768 * 4);
  unsigned short* xlb  = (unsigned short*)alloc((size_t)NNODE * OUTC * 2);
  unsigned short* xrb  = (unsigned short*)alloc((size_t)NNODE * OUTC * 2);
  unsigned short* xsb  = (unsigned short*)alloc((size_t)NNODE * OUTC * 2);
  int*            cnt  = (int*)alloc((size_t)NNODE * 4);
  float*          logits  = (float*)alloc((size_t)NNODE * 4);
  // slot arrays overlay xb (dead after gemm)
  int*   slot_src = (int*)xb;
  float* slot_e   = (float*)(xb + (size_t)NNODE * SLOTCAP * 2);
  (void)ws_size; (void)in_sizes; (void)n_in; (void)out_size;

  cvt_x_kernel<<<(NNODE * INC) / (256 * 8), 256, 0, stream>>>(x, xb, cnt);
  prep_w_kernel<<<(768 * 512 + 255) / 256, 256, 0, stream>>>(W_l, W_r, W_self, b_l, b_r, b_self, WT, bcat);
  gemm_kernel<<<768, 512, 0, stream>>>(xb, WT, bcat, xlb, xrb, xsb);
  edge_logit_kernel<<<ETOT / 8, 256, 0, stream>>>(ei, xlb, xrb, att, cnt, slot_src, slot_e);
  node_kernel<<<NNODE / 4, 256, 0, stream>>>(cnt, slot_src, slot_e, xlb, xsb, conv_bias,
                                             out, W_cls, b_cls, logits);
  sk_kernel<<<1024, 256, 0, stream>>>(logits, out);
}

// Round 9
// 191.429 us; speedup vs baseline: 1.2796x; 1.0438x over previous
//
#include <hip/hip_runtime.h>
#include <hip/hip_bf16.h>
#include <stdint.h>

#define NNODE 65536
#define NEDGE 65536
#define ETOT  (NNODE + NEDGE)
#define INC   512
#define OUTC  256
#define NEG_SLOPE 0.2f
#define SLOTCAP 32

typedef __attribute__((ext_vector_type(8))) __bf16 bf16x8;
typedef __attribute__((ext_vector_type(4))) float f32x4;

__device__ __forceinline__ float b2f(unsigned short u) {
  return __uint_as_float(((unsigned int)u) << 16);
}
__device__ __forceinline__ unsigned short f2b(float f) {
  unsigned int u = __float_as_uint(f);
  u += 0x7fffu + ((u >> 16) & 1u);
  return (unsigned short)(u >> 16);
}
__device__ __forceinline__ unsigned int pk2(float lo, float hi) {
  return (unsigned int)f2b(lo) | ((unsigned int)f2b(hi) << 16);
}
__device__ __forceinline__ float lrelu(float v) {
  return v > 0.f ? v : NEG_SLOPE * v;
}

// ---------------- prep: f32 -> bf16 of x (8 elems/lane) + cnt zeroing ----------
__global__ __launch_bounds__(256) void cvt_x_kernel(const float* __restrict__ x,
                                                    unsigned short* __restrict__ xb,
                                                    int* __restrict__ cnt) {
  if (blockIdx.x < 256) cnt[blockIdx.x * 256 + threadIdx.x] = 0;
  size_t i = ((size_t)blockIdx.x * 256 + threadIdx.x) * 8;
  float4 v0 = *(const float4*)(x + i);
  float4 v1 = *(const float4*)(x + i + 4);
  uint4 o;
  o.x = pk2(v0.x, v0.y);
  o.y = pk2(v0.z, v0.w);
  o.z = pk2(v1.x, v1.y);
  o.w = pk2(v1.z, v1.w);
  *(uint4*)(xb + i) = o;
}

// ---------------- prep: W concat transposed (768x512 bf16) + bias concat ----------------
__global__ __launch_bounds__(256) void prep_w_kernel(
    const float* __restrict__ Wl, const float* __restrict__ Wr, const float* __restrict__ Ws,
    const float* __restrict__ bl, const float* __restrict__ br, const float* __restrict__ bs,
    unsigned short* __restrict__ WT, float* __restrict__ bcat) {
  int i = blockIdx.x * 256 + threadIdx.x;
  if (i < 768 * 512) {
    int o = i >> 9, k = i & 511;
    float v;
    if (o < 256)      v = Wl[k * 256 + o];
    else if (o < 512) v = Wr[k * 256 + (o - 256)];
    else              v = Ws[k * 256 + (o - 512)];
    WT[i] = f2b(v);
  }
  if (i < 768) {
    bcat[i] = (i < 256) ? bl[i] : (i < 512 ? br[i - 256] : bs[i - 512]);
  }
}

// ---------------- fused GEMM (R8 8-phase core) + fused GEMV epilogue ------------------
// Adds: by=0 blocks emit g[row]=dot(xl_row,Wcls); by=2 blocks emit gs[row]=dot(xs_row,Wcls).
// Each block owns the FULL 256-col row -> deterministic block-local LDS reduce (no atomics).
__global__ __launch_bounds__(512) void gemm_kernel(
    const unsigned short* __restrict__ Xb,   // [65536][512]
    const unsigned short* __restrict__ WT,   // [768][512]
    const float* __restrict__ bcat,          // [768]
    const float* __restrict__ Wcls,          // [256]
    unsigned short* __restrict__ xl,
    unsigned short* __restrict__ xr,
    unsigned short* __restrict__ xs,
    float* __restrict__ g,                   // [65536] dot(xl,Wcls)
    float* __restrict__ gs) {                // [65536] dot(xs,Wcls)
  __shared__ __align__(16) char smem[98304];      // ring: 3 bufs x (A 16KB + B 16KB)
  unsigned short* ring = (unsigned short*)smem;   // buf b at b*16384 shorts; B at +8192

  const int wid = blockIdx.x;
  const int xcd = wid & 7;
  const int local = wid >> 3;              // 0..95
  const int by = local % 3;                // col tile 0..2  (0->xl, 1->xr, 2->xs)
  const int rowt = xcd * 32 + local / 3;   // row tile 0..255
  const int rowBase = rowt * 256;
  const int colBase = by * 256;

  const int tid = threadIdx.x;
  const int lane = tid & 63;
  const int w = tid >> 6;        // wave 0..7
  const int wm = (w >> 2) * 128; // wave row offset
  const int wn = (w & 3) * 64;   // wave col offset

  f32x4 acc[8][4] = {};

  auto stageh = [&](int c, int hf) {
    const int kk = c * 32;
    const int buf = c % 3;
    const int q = tid;
    const int sl = q & 3;
    const unsigned short* basep = hf ? (WT + (size_t)colBase * 512) : (Xb + (size_t)rowBase * 512);
    unsigned short* ldst = ring + buf * 16384 + hf * 8192;
#pragma unroll
    for (int l = 0; l < 2; ++l) {
      const int r = l * 128 + (q >> 2);            // tile row 0..255
      const int slot = sl ^ ((r >> 1) & 3);        // involution (rule 21)
      const unsigned short* gp = basep + (size_t)r * 512 + kk + slot * 8;
      __builtin_amdgcn_global_load_lds(
          (const __attribute__((address_space(1))) void*)gp,
          (__attribute__((address_space(3))) void*)(ldst + l * 4096 + q * 8), 16, 0, 0);
    }
  };

  // prologue: tiles 0 and 1 staged; tile 0 landed
  stageh(0, 0); stageh(0, 1);
  stageh(1, 0); stageh(1, 1);
  asm volatile("s_waitcnt vmcnt(4)" ::: "memory");
  __builtin_amdgcn_s_barrier();

#pragma unroll
  for (int c = 0; c < 16; ++c) {
    const unsigned short* As = ring + (c % 3) * 16384;
    const unsigned short* Bs = As + 8192;
    const int kq = lane >> 4;
    bf16x8 fa[8], fb[4];

    // ---- even phase: read A m0-3 + B n0-3; stage A-half of tile c+2 ----
#pragma unroll
    for (int m = 0; m < 4; ++m) {
      const int rA = wm + m * 16 + (lane & 15);
      fa[m] = *(const bf16x8*)&As[rA * 32 + ((kq ^ ((rA >> 1) & 3)) << 3)];
    }
#pragma unroll
    for (int n = 0; n < 4; ++n) {
      const int rB = wn + n * 16 + (lane & 15);
      fb[n] = *(const bf16x8*)&Bs[rB * 32 + ((kq ^ ((rB >> 1) & 3)) << 3)];
    }
    if (c + 2 < 16) stageh(c + 2, 0);
    __builtin_amdgcn_s_barrier();
    asm volatile("s_waitcnt lgkmcnt(0)" ::: "memory");
    __builtin_amdgcn_sched_barrier(0);
    __builtin_amdgcn_s_setprio(1);
#pragma unroll
    for (int m = 0; m < 4; ++m)
#pragma unroll
      for (int n = 0; n < 4; ++n)
        acc[m][n] = __builtin_amdgcn_mfma_f32_16x16x32_bf16(fa[m], fb[n], acc[m][n], 0, 0, 0);
    __builtin_amdgcn_s_setprio(0);
    __builtin_amdgcn_s_barrier();

    // ---- odd phase: read A m4-7; stage B-half of tile c+2 ----
#pragma unroll
    for (int m = 4; m < 8; ++m) {
      const int rA = wm + m * 16 + (lane & 15);
      fa[m] = *(const bf16x8*)&As[rA * 32 + ((kq ^ ((rA >> 1) & 3)) << 3)];
    }
    if (c + 2 < 16) stageh(c + 2, 1);
    __builtin_amdgcn_s_barrier();
    asm volatile("s_waitcnt lgkmcnt(0)" ::: "memory");
    __builtin_amdgcn_sched_barrier(0);
    __builtin_amdgcn_s_setprio(1);
#pragma unroll
    for (int m = 4; m < 8; ++m)
#pragma unroll
      for (int n = 0; n < 4; ++n)
        acc[m][n] = __builtin_amdgcn_mfma_f32_16x16x32_bf16(fa[m], fb[n], acc[m][n], 0, 0, 0);
    __builtin_amdgcn_s_setprio(0);
    if (c <= 13)      asm volatile("s_waitcnt vmcnt(4)" ::: "memory");
    else if (c == 14) asm volatile("s_waitcnt vmcnt(0)" ::: "memory");
    __builtin_amdgcn_s_barrier();
  }

  // epilogue: bf16 stores via per-wave-private LDS restage + fused row-dot (g/gs).
  // D frag layout: col = lane&15, row = (lane>>4)*4 + j   [m89-verified]
  {
    unsigned short* dst = (by == 0) ? xl : (by == 1) ? xr : xs;
    const bool doG = (by != 1);
    float* eps = (float*)smem + w * 1088;          // 16x68 f32 private (<= 34816B)
    float* gpart = (float*)(smem + 40960);         // [256][4] f32 = 4KB
    float biasn[4], wcn[4];
#pragma unroll
    for (int n = 0; n < 4; ++n) {
      biasn[n] = bcat[colBase + wn + n * 16 + (lane & 15)];
      wcn[n] = Wcls[wn + n * 16 + (lane & 15)];
    }
#pragma unroll
    for (int m = 0; m < 8; ++m) {
      float rp[4] = {0.f, 0.f, 0.f, 0.f};
#pragma unroll
      for (int n = 0; n < 4; ++n)
#pragma unroll
        for (int j = 0; j < 4; ++j) {
          const float v = acc[m][n][j] + biasn[n];
          eps[((lane >> 4) * 4 + j) * 68 + n * 16 + (lane & 15)] = v;
          rp[j] += v * wcn[n];
        }
#pragma unroll
      for (int it = 0; it < 2; ++it) {
        const int r16 = it * 8 + (lane >> 3);
        const int c8 = (lane & 7) * 8;
        const float* srcp = eps + r16 * 68 + c8;
        float4 v0 = *(const float4*)srcp;
        float4 v1 = *(const float4*)(srcp + 4);
        uint4 o;
        o.x = pk2(v0.x, v0.y);
        o.y = pk2(v0.z, v0.w);
        o.z = pk2(v1.x, v1.y);
        o.w = pk2(v1.z, v1.w);
        *(uint4*)(dst + (size_t)(rowBase + wm + m * 16 + r16) * 256 + wn + c8) = o;
      }
      if (doG) {
#pragma unroll
        for (int j = 0; j < 4; ++j) {
          float s = rp[j];
          s += __shfl_xor(s, 1);
          s += __shfl_xor(s, 2);
          s += __shfl_xor(s, 4);
          s += __shfl_xor(s, 8);
          if ((lane & 15) == 0)
            gpart[(wm + m * 16 + (lane >> 4) * 4 + j) * 4 + (w & 3)] = s;
        }
      }
    }
    __syncthreads();
    if (doG && tid < 256) {
      float s = gpart[tid * 4] + gpart[tid * 4 + 1] + gpart[tid * 4 + 2] + gpart[tid * 4 + 3];
      ((by == 0) ? g : gs)[rowBase + tid] = s;
    }
  }
}

// ---------------- per-edge attention logits (half-wave per edge) + direct slot scatter ----------------
__global__ __launch_bounds__(256) void edge_logit_kernel(
    const int* __restrict__ ei,          // [2][NEDGE]
    const unsigned short* __restrict__ xl,
    const unsigned short* __restrict__ xr,
    const float* __restrict__ att,
    int* __restrict__ cnt,
    int* __restrict__ slot_src,          // [NNODE][SLOTCAP]
    float* __restrict__ slot_e) {        // [NNODE][SLOTCAP]
  const int j = blockIdx.x * 8 + (threadIdx.x >> 5);
  const int lane = threadIdx.x & 31;
  int src, dst;
  if (j < NEDGE) { src = ei[j]; dst = ei[NEDGE + j]; }
  else           { src = j - NEDGE; dst = src; }
  const int c = lane * 8;
  uint4 ul = *(const uint4*)(xl + (size_t)src * 256 + c);
  uint4 ur = *(const uint4*)(xr + (size_t)dst * 256 + c);
  float4 a0 = *(const float4*)(att + c);
  float4 a1 = *(const float4*)(att + c + 4);
  float s = lrelu(b2f((unsigned short)ul.x) + b2f((unsigned short)ur.x)) * a0.x
          + lrelu(b2f((unsigned short)(ul.x >> 16)) + b2f((unsigned short)(ur.x >> 16))) * a0.y
          + lrelu(b2f((unsigned short)ul.y) + b2f((unsigned short)ur.y)) * a0.z
          + lrelu(b2f((unsigned short)(ul.y >> 16)) + b2f((unsigned short)(ur.y >> 16))) * a0.w
          + lrelu(b2f((unsigned short)ul.z) + b2f((unsigned short)ur.z)) * a1.x
          + lrelu(b2f((unsigned short)(ul.z >> 16)) + b2f((unsigned short)(ur.z >> 16))) * a1.y
          + lrelu(b2f((unsigned short)ul.w) + b2f((unsigned short)ur.w)) * a1.z
          + lrelu(b2f((unsigned short)(ul.w >> 16)) + b2f((unsigned short)(ur.w >> 16))) * a1.w;
#pragma unroll
  for (int off = 16; off; off >>= 1) s += __shfl_xor(s, off);
  if (lane == 0) {
    const int pos = atomicAdd(&cnt[dst], 1);
    if (pos < SLOTCAP) {
      slot_src[dst * SLOTCAP + pos] = src;
      slot_e[dst * SLOTCAP + pos] = s;
    }
  }
}

// ---------------- per-node cls logit from g/gs (thread per node; softmax is shift-invariant,
// so the dot(conv_bias,Wcls)+bcls constant cancels and is omitted) ----------------
__global__ __launch_bounds__(256) void logit_kernel(
    const int* __restrict__ cnt,
    const int* __restrict__ slot_src, const float* __restrict__ slot_e,
    const float* __restrict__ g, const float* __restrict__ gs,
    float* __restrict__ logits) {
  const int n = blockIdx.x * 256 + threadIdx.x;
  const int base = n * SLOTCAP;
  const int deg = cnt[n];
  float m = -1e30f;
  for (int k = 0; k < deg; ++k) m = fmaxf(m, slot_e[base + k]);
  float denom = 0.f, wsum = 0.f;
  for (int k = 0; k < deg; ++k) {
    const float p = __expf(slot_e[base + k] - m);
    denom += p;
    wsum += p * g[slot_src[base + k]];
  }
  logits[n] = gs[n] + wsum / denom;
}

// ---------------- per-node softmax + aggregate + fused sinkhorn add (wave per node) ----------------
__global__ __launch_bounds__(256) void node_sk_kernel(
    const int* __restrict__ cnt,
    const int* __restrict__ slot_src, const float* __restrict__ slot_e,
    const unsigned short* __restrict__ xl,
    const unsigned short* __restrict__ xs,
    const float* __restrict__ conv_bias,
    const float* __restrict__ logits,
    float* __restrict__ out) {
  const int n = blockIdx.x * 4 + (threadIdx.x >> 6);
  const int lane = threadIdx.x & 63;
  const int base = n * SLOTCAP;
  const int deg = cnt[n];

  float m = -1e30f;
  for (int k = 0; k < deg; ++k) m = fmaxf(m, slot_e[base + k]);
  float denom = 0.f;
  for (int k = 0; k < deg; ++k) denom += __expf(slot_e[base + k] - m);
  const float inv = 1.f / denom;

  const int c = lane * 4;
  float4 accv = {0.f, 0.f, 0.f, 0.f};
  for (int k = 0; k < deg; ++k) {
    const float alpha = __expf(slot_e[base + k] - m) * inv;
    const int src = slot_src[base + k];
    ushort4 u = *(const ushort4*)(xl + (size_t)src * 256 + c);
    accv.x += alpha * b2f(u.x);
    accv.y += alpha * b2f(u.y);
    accv.z += alpha * b2f(u.z);
    accv.w += alpha * b2f(u.w);
  }

  // row softmax of logits (sinkhorn channel): wave holds all 256 row logits (4/lane)
  const int r = n >> 8;
  float4 lv = *(const float4*)(logits + r * 256 + c);
  float lm = fmaxf(fmaxf(lv.x, lv.y), fmaxf(lv.z, lv.w));
#pragma unroll
  for (int off = 32; off; off >>= 1) lm = fmaxf(lm, __shfl_xor(lm, off));
  float ls = __expf(lv.x - lm) + __expf(lv.y - lm) + __expf(lv.z - lm) + __expf(lv.w - lm);
#pragma unroll
  for (int off = 32; off; off >>= 1) ls += __shfl_xor(ls, off);
  const float softval = __expf(logits[n] - lm) / ls;

  ushort4 s4 = *(const ushort4*)(xs + (size_t)n * 256 + c);
  float4 cb = *(const float4*)(conv_bias + c);
  float4 cur;
  cur.x = b2f(s4.x) + accv.x + cb.x + softval;
  cur.y = b2f(s4.y) + accv.y + cb.y + softval;
  cur.z = b2f(s4.z) + accv.z + cb.z + softval;
  cur.w = b2f(s4.w) + accv.w + cb.w + softval;
  *(float4*)(out + (size_t)n * 256 + c) = cur;
}

// ---------------- launch ----------------
extern "C" void kernel_launch(void* const* d_in, const int* in_sizes, int n_in,
                              void* d_out, int out_size, void* d_ws, size_t ws_size,
                              hipStream_t stream) {
  const float* x        = (const float*)d_in[0];
  const int*   ei       = (const int*)d_in[2];
  const float* W_self   = (const float*)d_in[5];
  const float* b_self   = (const float*)d_in[6];
  const float* W_l      = (const float*)d_in[7];
  const float* b_l      = (const float*)d_in[8];
  const float* W_r      = (const float*)d_in[9];
  const float* b_r      = (const float*)d_in[10];
  const float* att      = (const float*)d_in[11];
  const float* conv_bias= (const float*)d_in[12];
  const float* W_cls    = (const float*)d_in[13];
  float* out = (float*)d_out;

  char* ws = (char*)d_ws;
  size_t off = 0;
  auto alloc = [&](size_t bytes) {
    char* p = ws + off;
    off += (bytes + 255) & ~(size_t)255;
    return p;
  };
  unsigned short* xb   = (unsigned short*)alloc((size_t)NNODE * INC * 2);  // dead after gemm
  unsigned short* WT   = (unsigned short*)alloc((size_t)768 * 512 * 2);
  float*          bcat = (float*)alloc(768 * 4);
  unsigned short* xlb  = (unsigned short*)alloc((size_t)NNODE * OUTC * 2);
  unsigned short* xrb  = (unsigned short*)alloc((size_t)NNODE * OUTC * 2);
  unsigned short* xsb  = (unsigned short*)alloc((size_t)NNODE * OUTC * 2);
  int*            cnt  = (int*)alloc((size_t)NNODE * 4);
  float*          logits  = (float*)alloc((size_t)NNODE * 4);
  float*          gbuf    = (float*)alloc((size_t)NNODE * 4);
  float*          gsbuf   = (float*)alloc((size_t)NNODE * 4);
  // slot arrays overlay xb (dead after gemm)
  int*   slot_src = (int*)xb;
  float* slot_e   = (float*)(xb + (size_t)NNODE * SLOTCAP * 2);
  (void)ws_size; (void)in_sizes; (void)n_in; (void)out_size;

  cvt_x_kernel<<<(NNODE * INC) / (256 * 8), 256, 0, stream>>>(x, xb, cnt);
  prep_w_kernel<<<(768 * 512 + 255) / 256, 256, 0, stream>>>(W_l, W_r, W_self, b_l, b_r, b_self, WT, bcat);
  gemm_kernel<<<768, 512, 0, stream>>>(xb, WT, bcat, W_cls, xlb, xrb, xsb, gbuf, gsbuf);
  edge_logit_kernel<<<ETOT / 8, 256, 0, stream>>>(ei, xlb, xrb, att, cnt, slot_src, slot_e);
  logit_kernel<<<NNODE / 256, 256, 0, stream>>>(cnt, slot_src, slot_e, gbuf, gsbuf, logits);
  node_sk_kernel<<<NNODE / 4, 256, 0, stream>>>(cnt, slot_src, slot_e, xlb, xsb, conv_bias,
                                                logits, out);
}